// Round 3
// baseline (770.090 us; speedup 1.0000x reference)
//
#include <hip/hip_runtime.h>
#include <math.h>

// Problem constants (reference: N_CENTER=4000, N_NEIGH=16, N_FEAT=64)
#define NNEI   16
#define NFEAT  64
#define NPAIR  240              // 16*15 off-diagonal pairs
#define ROWW   195              // 1 + 1 + 1 + 64 + 64 + 64
#define PER_C  (NPAIR * ROWW)   // 46800 floats per center
#define COS_EPS 1e-8f

typedef float f32x4 __attribute__((ext_vector_type(4)));

// LDS value layout (flat word indices, PRE-swizzle):
//   [0   .. 255 ]  ang[j*16+k]
//   [256 .. 271 ]  d[n]
//   [272 .. 335 ]  emb_i[f]
//   [336 .. 1359]  embd[n*64+f] = emb(neighbor n)[f] / d[n]
//
// Bank swizzle (kept from R1, proven harmless): XOR low two word bits with
// bits [6:5]; bijective involution within each aligned 4-word group.
__device__ __forceinline__ int swz(int w) { return w ^ ((w >> 5) & 3); }

// flat (pair p, slot s) -> swizzled LDS word offset. Pure VALU (magic-mul
// for /15, cndmask chain for segment classify) — replaces the u16 offset
// table so the streaming loop's vmcnt contains ONLY stores (no load waits
// serialized behind store retirement).
__device__ __forceinline__ int off_of(int p, int s) {
    const unsigned ju = (unsigned)p / 15u;      // magic-mul
    const int j = (int)ju;
    const int r = p - (int)ju * 15;
    const int k = r + (r >= j);
    int off;
    if      (s >= 131) off = 336 + (k << 6) + (s - 131);   // emb_k / d_ik
    else if (s >= 67)  off = 336 + (j << 6) + (s - 67);    // emb_j / d_ij
    else if (s >= 3)   off = 269 + s;                      // emb_i
    else if (s == 2)   off = (j << 4) + k;                 // ang
    else if (s == 1)   off = 256 + k;                      // d_ik
    else               off = 256 + j;                      // d_ij
    return swz(off);
}

__global__ __launch_bounds__(256) void angdesc_kernel(
    const int*   __restrict__ atom_i_idx,
    const int*   __restrict__ atom_j_idx,
    const float* __restrict__ dist_ij,
    const float* __restrict__ atoms_xyz,
    const int*   __restrict__ atoms_long,
    const float* __restrict__ embed_table,
    float*       __restrict__ out0,   // (C,)       atom_i_idx as float
    float*       __restrict__ out1)   // (C,240,195)
{
    __shared__ float s_lds[1360];
    __shared__ float s_vec[NNEI][3];
    __shared__ float s_nrm[NNEI];
    __shared__ float s_invd[NNEI];
    __shared__ int   s_spec[NNEI];

    const int c   = blockIdx.x;
    const int tid = threadIdx.x;
    const int ii  = atom_i_idx[c];          // wave-uniform -> s_load

    if (tid == 0) out0[c] = (float)ii;

    const float xi = atoms_xyz[ii * 3 + 0];
    const float yi = atoms_xyz[ii * 3 + 1];
    const float zi = atoms_xyz[ii * 3 + 2];

    if (tid < NNEI) {
        const int jn = atom_j_idx[c * NNEI + tid];
        const float vx = atoms_xyz[jn * 3 + 0] - xi;
        const float vy = atoms_xyz[jn * 3 + 1] - yi;
        const float vz = atoms_xyz[jn * 3 + 2] - zi;
        s_vec[tid][0] = vx; s_vec[tid][1] = vy; s_vec[tid][2] = vz;
        s_nrm[tid]  = sqrtf(vx * vx + vy * vy + vz * vz);
        const float d = dist_ij[c * NNEI + tid];
        s_lds[swz(256 + tid)] = d;
        s_invd[tid] = 1.0f / d;
        s_spec[tid] = atoms_long[jn * 2 + 1];
    } else if (tid >= 64 && tid < 128) {
        const int f = tid - 64;
        const int speci = atoms_long[ii * 2 + 1];     // uniform
        s_lds[swz(272 + f)] = embed_table[speci * NFEAT + f];
    }
    __syncthreads();

    // Angle for every (j,k) in 16x16 (diagonal computed but never read).
    {
        const int j = tid >> 4, k = tid & 15;
        const float dot = s_vec[j][0] * s_vec[k][0]
                        + s_vec[j][1] * s_vec[k][1]
                        + s_vec[j][2] * s_vec[k][2];
        const float nj = fmaxf(s_nrm[j], COS_EPS);
        const float nk = fmaxf(s_nrm[k], COS_EPS);
        const float cosv = dot / (nj * nk);
        s_lds[swz(tid)] = acosf(cosv * 0.9999f);
    }
    // embd[n][f] = embed_table[spec[n]][f] / d[n]
    for (int e = tid; e < NNEI * NFEAT; e += 256) {
        const int n = e >> 6, f = e & 63;
        s_lds[swz(336 + e)] = embed_table[s_spec[n] * NFEAT + f] * s_invd[n];
    }
    __syncthreads();

    // Streaming loop. Per wave-iter: ~60 VALU (inline offset calc) +
    // 4x ds_read_b32 (swizzled) + 1x nontemporal global_store_dwordx4.
    // NO global loads -> vmcnt holds only fire-and-forget stores; the
    // only dependency waits are lgkmcnt on the 4 ds_reads.
    f32x4* __restrict__ dst4 = (f32x4*)(out1 + (size_t)c * PER_C);

    // Per-thread flat position e = 4*q, q = tid + 256*it.
    // Step per iteration: e += 1024 = 5*195 + 49  ->  p += 5, s += 49 (wrap).
    int p = (tid << 2) / 195;            // one-time magic-div
    int s = (tid << 2) - p * 195;
    #pragma unroll 2
    for (int q = tid; q < PER_C / 4; q += 256) {
        f32x4 v;
        #pragma unroll
        for (int i = 0; i < 4; ++i) {
            int pp = p, ss = s + i;
            if (ss >= 195) { pp += 1; ss -= 195; }
            v[i] = s_lds[off_of(pp, ss)];
        }
        __builtin_nontemporal_store(v, dst4 + q);
        s += 49; p += 5;
        if (s >= 195) { s -= 195; p += 1; }
    }
}

extern "C" void kernel_launch(void* const* d_in, const int* in_sizes, int n_in,
                              void* d_out, int out_size, void* d_ws, size_t ws_size,
                              hipStream_t stream) {
    // setup_inputs order: [0]=nNeigh, [1]=atom_i_idx, [2]=atom_j_idx,
    // [3]=dist_ij, [4]=atoms_xyz, [5]=atoms_long, [6]=embed_table
    const int*   atom_i_idx  = (const int*)  d_in[1];
    const int*   atom_j_idx  = (const int*)  d_in[2];
    const float* dist_ij     = (const float*)d_in[3];
    const float* atoms_xyz   = (const float*)d_in[4];
    const int*   atoms_long  = (const int*)  d_in[5];
    const float* embed_table = (const float*)d_in[6];

    const int C = in_sizes[1];              // 4000 centers
    float* out  = (float*)d_out;
    (void)d_ws; (void)ws_size;

    angdesc_kernel<<<C, 256, 0, stream>>>(atom_i_idx, atom_j_idx, dist_ij,
                                          atoms_xyz, atoms_long, embed_table,
                                          out, out + C);
}